// Round 6
// baseline (335.689 us; speedup 1.0000x reference)
//
#include <hip/hip_runtime.h>
#include <math.h>

#define NN 12000
#define NP 12032            // padded rows (94*128)
#define CCD 512
#define KK 4096
#define TT 1500
#define S20F 28.853900817779268f   // 20*log2(e)
#define SC2F 14.426950408889634f   // 10*log2(e)
#define LN2F 0.6931471805599453f

typedef float f32x4 __attribute__((ext_vector_type(4)));
typedef __bf16 bf16x8 __attribute__((ext_vector_type(8)));

__device__ __forceinline__ ushort f2bf(float f){
  uint u = __float_as_uint(f);
  uint r = (u + 0x7fffu + ((u >> 16) & 1u)) >> 16;
  return (ushort)r;
}
__device__ __forceinline__ float bf2f(ushort u){
  return __uint_as_float(((uint)u) << 16);
}

typedef __attribute__((address_space(1))) const unsigned int g_u32;
typedef __attribute__((address_space(3))) unsigned int l_u32;
__device__ __forceinline__ void gload_lds16(const void* g, void* l){
  __builtin_amdgcn_global_load_lds((g_u32*)g, (l_u32*)l, 16, 0, 0);
}

// ---- student (B,C,T) f32 -> zbf[N][C] bf16 (tiled transpose) ----
__global__ __launch_bounds__(256) void k_prep_z(const float* __restrict__ src, ushort* __restrict__ dst){
  __shared__ float tile[64][65];
  int b = blockIdx.z, c0 = blockIdx.y*64, t0 = blockIdx.x*64;
  const float* sb = src + ((size_t)b*CCD + c0)*TT + t0;
  for (int i = 0; i < 16; ++i){
    int e = i*256 + threadIdx.x;
    int cl = e >> 6, tl = e & 63;
    if (t0 + tl < TT) tile[cl][tl] = sb[(size_t)cl*TT + tl];
  }
  __syncthreads();
  for (int i = 0; i < 16; ++i){
    int e = i*256 + threadIdx.x;
    int tl = e >> 6, cl = e & 63;
    if (t0 + tl < TT) dst[((size_t)b*TT + t0 + tl)*CCD + c0 + cl] = f2bf(tile[cl][tl]);
  }
}

// ---- codebook f32 -> pre-swizzled bf16 LDS-image layout (64-code / 64KB tiles) ----
// image: [tile=64][65536 B]; within tile: code*1024 + cc*256 + slot*16,
// slot = g_src ^ (code&7), g_src = 16B-chunk (8 bf16) index within cc-block.
__global__ __launch_bounds__(256) void k_prep_cb(const float* __restrict__ cb, ushort* __restrict__ cbsw){
  int id = blockIdx.x*256 + threadIdx.x;     // [0, 262144) uint4 slots
  int gs   = id & 15;
  int cc   = (id >> 4) & 3;
  int code = (id >> 6) & 63;
  int tile = id >> 12;
  int g = gs ^ (code & 7);
  const float* src = cb + (((size_t)(tile*64 + code))*CCD + cc*128 + g*8);
  float4 v0 = *(const float4*)src;
  float4 v1 = *(const float4*)(src + 4);
  uint4 o;
  o.x = (uint)f2bf(v0.x) | ((uint)f2bf(v0.y) << 16);
  o.y = (uint)f2bf(v0.z) | ((uint)f2bf(v0.w) << 16);
  o.z = (uint)f2bf(v1.x) | ((uint)f2bf(v1.y) << 16);
  o.w = (uint)f2bf(v1.z) | ((uint)f2bf(v1.w) << 16);
  ((uint4*)cbsw)[id] = o;
}

// ---- per-code scaled squared norms: c2s[k] = ||c_k||^2 * 10*log2e ----
__global__ __launch_bounds__(256) void k_c2(const float* __restrict__ cb, float* __restrict__ c2s){
  int k = blockIdx.x*4 + (threadIdx.x >> 6);
  int lane = threadIdx.x & 63;
  const float4* p = (const float4*)(cb + (size_t)k*CCD);
  float s = 0.f;
  for (int i = lane; i < CCD/4; i += 64){
    float4 v = p[i];
    s += v.x*v.x + v.y*v.y + v.z*v.z + v.w*v.w;
  }
  for (int off=1; off<64; off<<=1) s += __shfl_xor(s, off);
  if (lane == 0) c2s[k] = s * SC2F;
}

// ---- fused bf16-MFMA distance GEMM, A in regs, B 64KB ping-pong LDS tiles ----
// grid (8, 94): x = ksplit (512 codes), y = row block (128 rows)
// bid%8 == ksplit -> each XCD keeps its 512KB codebook slice L2-resident.
// STATIC 128KB LDS: lets the RA see occupancy is 1 block (2 waves/EU) and
// budget 256 VGPRs — dynamic LDS made it target 4 waves/EU -> 128 cap -> spill.
__global__ __launch_bounds__(512) __attribute__((amdgpu_waves_per_eu(2)))
void k_dist(const ushort* __restrict__ zbf,
    const ushort* __restrict__ cbsw, const float* __restrict__ c2s,
    const int* __restrict__ codes, float4* __restrict__ pstate){
  __shared__ char cs[2*65536];
  int tid = threadIdx.x, w = tid >> 6, l = tid & 63;
  int lm = l & 15, k16 = l >> 4;
  int yk = blockIdx.x, xb = blockIdx.y;
  int n0 = xb * 128, kb = yk * 512;
  int wr = w >> 1, wc = w & 1;

  // A fragments: 32 rows x 512 C per wave (128 VGPRs)
  bf16x8 A0[16], A1[16];
  {
    const ushort* a0 = zbf + (size_t)(n0 + wr*32 + lm)*CCD + k16*8;
#pragma unroll
    for (int u = 0; u < 16; ++u){
      A0[u] = *(const bf16x8*)(a0 + u*32);
      A1[u] = *(const bf16x8*)(a0 + 16*CCD + u*32);
    }
  }
  // target codes for the 8 rows this lane owns (for argmax exclusion)
  int tgt[8];
#pragma unroll
  for (int fi=0; fi<2; ++fi)
#pragma unroll
    for (int r=0; r<4; ++r)
      tgt[fi*4+r] = codes[n0 + wr*32 + fi*16 + k16*4 + r];

  float m2[8], ss[8], bv[8]; int bi[8];
#pragma unroll
  for (int i=0;i<8;++i){ m2[i]=-3.0e38f; ss[i]=0.f; bv[i]=-3.0e38f; bi[i]=0x7fffffff; }

#define STAGE(tile, buf) { \
    const char* tb_ = (const char*)cbsw + ((size_t)(yk*8 + (tile)))*65536; \
    _Pragma("unroll") \
    for (int j_ = 0; j_ < 8; ++j_) \
      gload_lds16(tb_ + w*8192 + j_*1024 + l*16, (buf) + w*8192 + j_*1024); }

  STAGE(0, cs)
  __syncthreads();

#pragma unroll
  for (int t = 0; t < 8; ++t){
    char* cur = cs + (t & 1)*65536;
    char* nxt = cs + ((t + 1) & 1)*65536;
    if (t < 7) STAGE(t + 1, nxt)     // issue next tile's loads before compute

    int colg0 = kb + t*64 + wc*32 + lm;
    float c2r0 = c2s[colg0], c2r1 = c2s[colg0 + 16];

    f32x4 acc[2][2];
#pragma unroll
    for (int fi=0; fi<2; ++fi)
#pragma unroll
      for (int fj=0; fj<2; ++fj) acc[fi][fj] = (f32x4){0.f,0.f,0.f,0.f};

#pragma unroll
    for (int cc2 = 0; cc2 < 4; ++cc2){
#pragma unroll
      for (int ks = 0; ks < 4; ++ks){
        bf16x8 b0, b1;
        {
          int code0 = wc*32 + lm;
          int code1 = code0 + 16;
          b0 = *(const bf16x8*)(cur + code0*1024 + cc2*256 + ((((ks*4)+k16) ^ (code0 & 7)) << 4));
          b1 = *(const bf16x8*)(cur + code1*1024 + cc2*256 + ((((ks*4)+k16) ^ (code1 & 7)) << 4));
        }
        acc[0][0] = __builtin_amdgcn_mfma_f32_16x16x32_bf16(A0[cc2*4+ks], b0, acc[0][0], 0,0,0);
        acc[0][1] = __builtin_amdgcn_mfma_f32_16x16x32_bf16(A0[cc2*4+ks], b1, acc[0][1], 0,0,0);
        acc[1][0] = __builtin_amdgcn_mfma_f32_16x16x32_bf16(A1[cc2*4+ks], b0, acc[1][0], 0,0,0);
        acc[1][1] = __builtin_amdgcn_mfma_f32_16x16x32_bf16(A1[cc2*4+ks], b1, acc[1][1], 0,0,0);
      }
    }

    // epilogue: argmax (tgt-excluded) + online softmax (all cols)
#pragma unroll
    for (int fi=0; fi<2; ++fi)
#pragma unroll
    for (int r=0; r<4; ++r){
      int i8 = fi*4 + r;
      float v0 = fmaf(acc[fi][0][r], S20F, -c2r0);
      float v1 = fmaf(acc[fi][1][r], S20F, -c2r1);
      int c0 = colg0, c1 = colg0 + 16;
      if (c0 != tgt[i8] && v0 > bv[i8]){ bv[i8] = v0; bi[i8] = c0; }
      if (c1 != tgt[i8] && v1 > bv[i8]){ bv[i8] = v1; bi[i8] = c1; }
      float tm = fmaxf(v0, v1);
      float mn = fmaxf(m2[i8], tm);
      ss[i8] = ss[i8]*exp2f(m2[i8]-mn) + exp2f(v0-mn) + exp2f(v1-mn);
      m2[i8] = mn;
    }
    __syncthreads();   // next tile staged; all reads of cur done
  }
#undef STAGE

  // butterfly over the 16 lanes sharing each row
#pragma unroll
  for (int off = 1; off < 16; off <<= 1){
#pragma unroll
    for (int i=0; i<8; ++i){
      float mo = __shfl_xor(m2[i], off);
      float so = __shfl_xor(ss[i], off);
      float bvo = __shfl_xor(bv[i], off);
      int  bio = __shfl_xor(bi[i], off);
      if (bvo > bv[i] || (bvo == bv[i] && bio < bi[i])){ bv[i] = bvo; bi[i] = bio; }
      float mn = fmaxf(m2[i], mo);
      ss[i] = ss[i]*exp2f(m2[i]-mn) + so*exp2f(mo-mn);
      m2[i] = mn;
    }
  }
  if (lm == 0){
#pragma unroll
    for (int fi=0; fi<2; ++fi)
#pragma unroll
    for (int r=0; r<4; ++r){
      int i8 = fi*4 + r;
      int row = wr*32 + fi*16 + k16*4 + r;
      pstate[((size_t)(yk*2 + wc))*NP + n0 + row] =
          make_float4(m2[i8], ss[i8], bv[i8], __int_as_float(bi[i8]));
    }
  }
}

// ---- merge the 16 partials per row ----
__global__ __launch_bounds__(256) void k_merge(const float4* __restrict__ pstate,
    float* __restrict__ lse2, int* __restrict__ hard){
  int n = blockIdx.x*256 + threadIdx.x;
  if (n >= NN) return;
  float m=-3.0e38f, s=0.f, bv=-3.0e38f; int bi=0x7fffffff;
  for (int sp = 0; sp < 16; ++sp){
    float4 p = pstate[(size_t)sp*NP + n];
    int pb = __float_as_int(p.w);
    if (p.z > bv || (p.z == bv && pb < bi)){ bv = p.z; bi = pb; }
    float mn = fmaxf(m, p.x);
    s = s*exp2f(m - mn) + p.y*exp2f(p.x - mn);
    m = mn;
  }
  lse2[n] = m + log2f(s);
  hard[n] = bi;
}

// ---- finalize: triplet + direction + feature + exact fp32 logit[tgt] -> ce ----
__global__ __launch_bounds__(256) void k_final(const float* __restrict__ student,
    const float* __restrict__ teacher, const float* __restrict__ orig,
    const float* __restrict__ cb, const int* __restrict__ hard,
    const int* __restrict__ codes, const float* __restrict__ lse2,
    const float* __restrict__ c2s, float* __restrict__ accs){
  __shared__ float red[6][4][64];
  int tt = threadIdx.x & 63, cg = threadIdx.x >> 6;
  int n = blockIdx.x*64 + tt;
  float dp2=0,dn2=0,mm=0,dd=0,md=0,dt=0;
  bool ok = (n < NN);
  int tg = 0;
  if (ok){
    int hn = hard[n]; tg = codes[n];
    int b = n / TT, t = n - b*TT;
    size_t base = (size_t)b*CCD*TT + t;
    const float* ch = cb + (size_t)hn*CCD;
    const float* ct = cb + (size_t)tg*CCD;
    for (int c = cg*128; c < cg*128+128; ++c){
      float sv = student[base + (size_t)c*TT];
      float tv = teacher[base + (size_t)c*TT];
      float ov = orig[base + (size_t)c*TT];
      float cv = ch[c], wv = ct[c];
      float u = sv - tv; dp2 = fmaf(u,u,dp2);
      float v = tv - cv; dn2 = fmaf(v,v,dn2);
      float mv = sv - ov, dv = tv - ov;
      mm = fmaf(mv,mv,mm); dd = fmaf(dv,dv,dd); md = fmaf(mv,dv,md);
      dt = fmaf(sv, wv, dt);
    }
  }
  red[0][cg][tt]=dp2; red[1][cg][tt]=dn2; red[2][cg][tt]=mm;
  red[3][cg][tt]=dd;  red[4][cg][tt]=md;  red[5][cg][tt]=dt;
  __syncthreads();
  if (cg == 0){
    dp2 = red[0][0][tt]+red[0][1][tt]+red[0][2][tt]+red[0][3][tt];
    dn2 = red[1][0][tt]+red[1][1][tt]+red[1][2][tt]+red[1][3][tt];
    mm  = red[2][0][tt]+red[2][1][tt]+red[2][2][tt]+red[2][3][tt];
    dd  = red[3][0][tt]+red[3][1][tt]+red[3][2][tt]+red[3][3][tt];
    md  = red[4][0][tt]+red[4][1][tt]+red[4][2][tt]+red[4][3][tt];
    dt  = red[5][0][tt]+red[5][1][tt]+red[5][2][tt]+red[5][3][tt];
    float trip=0.f, dc=0.f, nv=0.f, ce=0.f;
    if (ok){
      float dpos = sqrtf(dp2), dneg = sqrtf(dn2);
      trip = fmaxf(dpos - dneg + 0.5f, 0.f);
      float mn = sqrtf(mm), dnn = sqrtf(dd);
      bool valid = (mn > 1e-6f) && (dnn > 1e-6f);
      float cosv = md / ((mn + 1e-8f)*(dnn + 1e-8f));
      if (valid){ dc = 1.f - cosv; nv = 1.f; }
      ce = lse2[n] - (fmaf(dt, S20F, -c2s[tg]));
    }
    for (int off=1; off<64; off<<=1){
      trip += __shfl_xor(trip,off);
      dc   += __shfl_xor(dc,off);
      nv   += __shfl_xor(nv,off);
      dp2  += __shfl_xor(dp2,off);
      ce   += __shfl_xor(ce,off);
    }
    if (tt == 0){
      atomicAdd(&accs[0], trip); atomicAdd(&accs[1], dc);
      atomicAdd(&accs[2], nv);   atomicAdd(&accs[3], dp2);
      atomicAdd(&accs[4], ce);
    }
  }
}

__global__ void k_total(const float* __restrict__ accs, float* __restrict__ out){
  float feat = accs[3] / 6144000.f;         // 8*512*1500
  float trip = accs[0] / (float)NN;
  float ce   = (accs[4] / (float)NN) * LN2F;
  float nv   = accs[2] < 1.f ? 1.f : accs[2];
  float dc   = accs[1] / nv;
  out[0] = 2.f*feat + trip + ce + dc;
}

extern "C" void kernel_launch(void* const* d_in, const int* in_sizes, int n_in,
                              void* d_out, int out_size, void* d_ws, size_t ws_size,
                              hipStream_t stream){
  const float* student = (const float*)d_in[0];
  const float* teacher = (const float*)d_in[1];
  const float* cb      = (const float*)d_in[2];
  const int*   codes   = (const int*)d_in[3];
  const float* orig    = (const float*)d_in[4];

  char* ws = (char*)d_ws;
  ushort* zbf    = (ushort*)(ws);                  // 12032*512*2 = 12,320,768
  ushort* cbsw   = (ushort*)(ws + 12320768);       // 4,194,304
  float*  c2s    = (float*)(ws + 16515072);        // 16,384
  float4* pstate = (float4*)(ws + 16531456);       // 16*12032*16 = 3,080,192
  float*  lse2   = (float*)(ws + 19611648);        // 48,128
  int*    hard   = (int*)(ws + 19659776);          // 48,128
  float*  accs   = (float*)(ws + 19707904);        // 8 floats
  hipMemsetAsync(ws + 19707904, 0, 64, stream);
  k_prep_cb<<<1024, 256, 0, stream>>>(cb, cbsw);
  k_c2<<<1024, 256, 0, stream>>>(cb, c2s);
  k_prep_z<<<dim3(24, 8, 8), 256, 0, stream>>>(student, zbf);
  k_dist<<<dim3(8, 94), 512, 0, stream>>>(zbf, cbsw, c2s, codes, pstate);
  k_merge<<<47, 256, 0, stream>>>(pstate, lse2, hard);
  k_final<<<188, 256, 0, stream>>>(student, teacher, orig, cb, hard, codes, lse2, c2s, accs);
  k_total<<<1, 1, 0, stream>>>(accs, (float*)d_out);
}

// Round 7
// 178.854 us; speedup vs baseline: 1.8769x; 1.8769x over previous
//
#include <hip/hip_runtime.h>
#include <math.h>

#define NN 12000
#define NP 12032            // padded rows (94*128)
#define CCD 512
#define KK 4096
#define TT 1500
#define S20F 28.853900817779268f   // 20*log2(e)
#define SC2F 14.426950408889634f   // 10*log2(e)
#define LN2F 0.6931471805599453f

typedef float f32x4 __attribute__((ext_vector_type(4)));
typedef __bf16 bf16x8 __attribute__((ext_vector_type(8)));

__device__ __forceinline__ ushort f2bf(float f){
  uint u = __float_as_uint(f);
  uint r = (u + 0x7fffu + ((u >> 16) & 1u)) >> 16;
  return (ushort)r;
}
__device__ __forceinline__ float bf2f(ushort u){
  return __uint_as_float(((uint)u) << 16);
}

typedef __attribute__((address_space(1))) const unsigned int g_u32;
typedef __attribute__((address_space(3))) unsigned int l_u32;
__device__ __forceinline__ void gload_lds16(const void* g, void* l){
  __builtin_amdgcn_global_load_lds((g_u32*)g, (l_u32*)l, 16, 0, 0);
}

// ---- student (B,C,T) f32 -> zbf[N][C] bf16 (tiled transpose) ----
__global__ __launch_bounds__(256) void k_prep_z(const float* __restrict__ src, ushort* __restrict__ dst){
  __shared__ float tile[64][65];
  int b = blockIdx.z, c0 = blockIdx.y*64, t0 = blockIdx.x*64;
  const float* sb = src + ((size_t)b*CCD + c0)*TT + t0;
  for (int i = 0; i < 16; ++i){
    int e = i*256 + threadIdx.x;
    int cl = e >> 6, tl = e & 63;
    if (t0 + tl < TT) tile[cl][tl] = sb[(size_t)cl*TT + tl];
  }
  __syncthreads();
  for (int i = 0; i < 16; ++i){
    int e = i*256 + threadIdx.x;
    int tl = e >> 6, cl = e & 63;
    if (t0 + tl < TT) dst[((size_t)b*TT + t0 + tl)*CCD + c0 + cl] = f2bf(tile[cl][tl]);
  }
}

// ---- codebook f32 -> pre-swizzled bf16 LDS-image layout (64-code / 64KB tiles) ----
// image: [tile=64][65536 B]; within tile: code*1024 + cc*256 + slot*16,
// slot = g_src ^ (code&7), g_src = 16B-chunk (8 bf16) index within cc-block.
__global__ __launch_bounds__(256) void k_prep_cb(const float* __restrict__ cb, ushort* __restrict__ cbsw){
  int id = blockIdx.x*256 + threadIdx.x;     // [0, 262144) uint4 slots
  int gs   = id & 15;
  int cc   = (id >> 4) & 3;
  int code = (id >> 6) & 63;
  int tile = id >> 12;
  int g = gs ^ (code & 7);
  const float* src = cb + (((size_t)(tile*64 + code))*CCD + cc*128 + g*8);
  float4 v0 = *(const float4*)src;
  float4 v1 = *(const float4*)(src + 4);
  uint4 o;
  o.x = (uint)f2bf(v0.x) | ((uint)f2bf(v0.y) << 16);
  o.y = (uint)f2bf(v0.z) | ((uint)f2bf(v0.w) << 16);
  o.z = (uint)f2bf(v1.x) | ((uint)f2bf(v1.y) << 16);
  o.w = (uint)f2bf(v1.z) | ((uint)f2bf(v1.w) << 16);
  ((uint4*)cbsw)[id] = o;
}

// ---- per-code scaled squared norms: c2s[k] = ||c_k||^2 * 10*log2e ----
__global__ __launch_bounds__(256) void k_c2(const float* __restrict__ cb, float* __restrict__ c2s){
  int k = blockIdx.x*4 + (threadIdx.x >> 6);
  int lane = threadIdx.x & 63;
  const float4* p = (const float4*)(cb + (size_t)k*CCD);
  float s = 0.f;
  for (int i = lane; i < CCD/4; i += 64){
    float4 v = p[i];
    s += v.x*v.x + v.y*v.y + v.z*v.z + v.w*v.w;
  }
  for (int off=1; off<64; off<<=1) s += __shfl_xor(s, off);
  if (lane == 0) c2s[k] = s * SC2F;
}

// ---- fused bf16-MFMA distance GEMM ----
// 8 waves x 16 rows/wave, each wave spans the full 64-code k-tile width.
// Per-lane A = 16 rows x 512 C = 64 VGPRs -> total ~125 regs, fits the
// 128-arch-VGPR cap the backend enforces for MFMA kernels (R4-R6 evidence:
// 32-rows/wave (128 VGPR A) spilled ~340MB to scratch at every hint setting).
// grid (8, 94): x = ksplit (512 codes), y = row block (128 rows)
// bid%8 == ksplit -> each XCD keeps its 512KB codebook slice L2-resident.
__global__ __launch_bounds__(512) void k_dist(const ushort* __restrict__ zbf,
    const ushort* __restrict__ cbsw, const float* __restrict__ c2s,
    const int* __restrict__ codes, float4* __restrict__ pstate){
  __shared__ char cs[2*65536];
  int tid = threadIdx.x, w = tid >> 6, l = tid & 63;
  int lm = l & 15, k16 = l >> 4;
  int yk = blockIdx.x, xb = blockIdx.y;
  int n0 = xb * 128, kb = yk * 512;

  // A fragments: 16 rows x 512 C per wave (64 VGPRs/lane)
  bf16x8 A[16];
  {
    const ushort* a0 = zbf + (size_t)(n0 + w*16 + lm)*CCD + k16*8;
#pragma unroll
    for (int u = 0; u < 16; ++u) A[u] = *(const bf16x8*)(a0 + u*32);
  }
  // target codes for the 4 rows this lane owns (for argmax exclusion)
  int tgt[4];
#pragma unroll
  for (int r = 0; r < 4; ++r){
    int n = n0 + w*16 + k16*4 + r;
    tgt[r] = (n < NN) ? codes[n] : -1;
  }

  float m2[4], ss[4], bv[4]; int bi[4];
#pragma unroll
  for (int i=0;i<4;++i){ m2[i]=-3.0e38f; ss[i]=0.f; bv[i]=-3.0e38f; bi[i]=0x7fffffff; }

#define STAGE(tile, buf) { \
    const char* tb_ = (const char*)cbsw + ((size_t)(yk*8 + (tile)))*65536; \
    _Pragma("unroll") \
    for (int j_ = 0; j_ < 8; ++j_) \
      gload_lds16(tb_ + w*8192 + j_*1024 + l*16, (buf) + w*8192 + j_*1024); }

  STAGE(0, cs)
  __syncthreads();

#pragma unroll
  for (int t = 0; t < 8; ++t){
    char* cur = cs + (t & 1)*65536;
    char* nxt = cs + ((t + 1) & 1)*65536;
    if (t < 7) STAGE(t + 1, nxt)     // issue next tile's loads before compute

    int colg0 = kb + t*64 + lm;

    f32x4 acc[4];
#pragma unroll
    for (int fj=0; fj<4; ++fj) acc[fj] = (f32x4){0.f,0.f,0.f,0.f};

#pragma unroll
    for (int cc2 = 0; cc2 < 4; ++cc2){
#pragma unroll
      for (int ks = 0; ks < 4; ++ks){
        bf16x8 b[4];
#pragma unroll
        for (int fj=0; fj<4; ++fj){
          int code = fj*16 + lm;
          b[fj] = *(const bf16x8*)(cur + code*1024 + cc2*256 + ((((ks*4)+k16) ^ (code & 7)) << 4));
        }
#pragma unroll
        for (int fj=0; fj<4; ++fj)
          acc[fj] = __builtin_amdgcn_mfma_f32_16x16x32_bf16(A[cc2*4+ks], b[fj], acc[fj], 0,0,0);
      }
    }

    // epilogue: argmax (tgt-excluded) + online softmax (all cols)
    float c2r[4];
#pragma unroll
    for (int fj=0; fj<4; ++fj) c2r[fj] = c2s[colg0 + fj*16];
#pragma unroll
    for (int r=0; r<4; ++r){
      float v[4];
#pragma unroll
      for (int fj=0; fj<4; ++fj) v[fj] = fmaf(acc[fj][r], S20F, -c2r[fj]);
#pragma unroll
      for (int fj=0; fj<4; ++fj){
        int cg = colg0 + fj*16;
        if (cg != tgt[r] && v[fj] > bv[r]){ bv[r] = v[fj]; bi[r] = cg; }
      }
      float tm = fmaxf(fmaxf(v[0], v[1]), fmaxf(v[2], v[3]));
      float mn = fmaxf(m2[r], tm);
      float s = ss[r]*exp2f(m2[r]-mn);
#pragma unroll
      for (int fj=0; fj<4; ++fj) s += exp2f(v[fj]-mn);
      ss[r] = s; m2[r] = mn;
    }
    __syncthreads();   // next tile staged; all reads of cur done
  }
#undef STAGE

  // butterfly over the 16 lanes sharing each row
#pragma unroll
  for (int off = 1; off < 16; off <<= 1){
#pragma unroll
    for (int i=0; i<4; ++i){
      float mo = __shfl_xor(m2[i], off);
      float so = __shfl_xor(ss[i], off);
      float bvo = __shfl_xor(bv[i], off);
      int  bio = __shfl_xor(bi[i], off);
      if (bvo > bv[i] || (bvo == bv[i] && bio < bi[i])){ bv[i] = bvo; bi[i] = bio; }
      float mn = fmaxf(m2[i], mo);
      ss[i] = ss[i]*exp2f(m2[i]-mn) + so*exp2f(mo-mn);
      m2[i] = mn;
    }
  }
  if (lm == 0){
#pragma unroll
    for (int r=0; r<4; ++r){
      int row = w*16 + k16*4 + r;
      pstate[(size_t)yk*NP + n0 + row] =
          make_float4(m2[r], ss[r], bv[r], __int_as_float(bi[r]));
    }
  }
}

// ---- merge the 8 partials per row ----
__global__ __launch_bounds__(256) void k_merge(const float4* __restrict__ pstate,
    float* __restrict__ lse2, int* __restrict__ hard){
  int n = blockIdx.x*256 + threadIdx.x;
  if (n >= NN) return;
  float m=-3.0e38f, s=0.f, bv=-3.0e38f; int bi=0x7fffffff;
  for (int sp = 0; sp < 8; ++sp){
    float4 p = pstate[(size_t)sp*NP + n];
    int pb = __float_as_int(p.w);
    if (p.z > bv || (p.z == bv && pb < bi)){ bv = p.z; bi = pb; }
    float mn = fmaxf(m, p.x);
    s = s*exp2f(m - mn) + p.y*exp2f(p.x - mn);
    m = mn;
  }
  lse2[n] = m + log2f(s);
  hard[n] = bi;
}

// ---- finalize: triplet + direction + feature + exact fp32 logit[tgt] -> ce ----
__global__ __launch_bounds__(256) void k_final(const float* __restrict__ student,
    const float* __restrict__ teacher, const float* __restrict__ orig,
    const float* __restrict__ cb, const int* __restrict__ hard,
    const int* __restrict__ codes, const float* __restrict__ lse2,
    const float* __restrict__ c2s, float* __restrict__ accs){
  __shared__ float red[6][4][64];
  int tt = threadIdx.x & 63, cg = threadIdx.x >> 6;
  int n = blockIdx.x*64 + tt;
  float dp2=0,dn2=0,mm=0,dd=0,md=0,dt=0;
  bool ok = (n < NN);
  int tg = 0;
  if (ok){
    int hn = hard[n]; tg = codes[n];
    int b = n / TT, t = n - b*TT;
    size_t base = (size_t)b*CCD*TT + t;
    const float* ch = cb + (size_t)hn*CCD;
    const float* ct = cb + (size_t)tg*CCD;
    for (int c = cg*128; c < cg*128+128; ++c){
      float sv = student[base + (size_t)c*TT];
      float tv = teacher[base + (size_t)c*TT];
      float ov = orig[base + (size_t)c*TT];
      float cv = ch[c], wv = ct[c];
      float u = sv - tv; dp2 = fmaf(u,u,dp2);
      float v = tv - cv; dn2 = fmaf(v,v,dn2);
      float mv = sv - ov, dv = tv - ov;
      mm = fmaf(mv,mv,mm); dd = fmaf(dv,dv,dd); md = fmaf(mv,dv,md);
      dt = fmaf(sv, wv, dt);
    }
  }
  red[0][cg][tt]=dp2; red[1][cg][tt]=dn2; red[2][cg][tt]=mm;
  red[3][cg][tt]=dd;  red[4][cg][tt]=md;  red[5][cg][tt]=dt;
  __syncthreads();
  if (cg == 0){
    dp2 = red[0][0][tt]+red[0][1][tt]+red[0][2][tt]+red[0][3][tt];
    dn2 = red[1][0][tt]+red[1][1][tt]+red[1][2][tt]+red[1][3][tt];
    mm  = red[2][0][tt]+red[2][1][tt]+red[2][2][tt]+red[2][3][tt];
    dd  = red[3][0][tt]+red[3][1][tt]+red[3][2][tt]+red[3][3][tt];
    md  = red[4][0][tt]+red[4][1][tt]+red[4][2][tt]+red[4][3][tt];
    dt  = red[5][0][tt]+red[5][1][tt]+red[5][2][tt]+red[5][3][tt];
    float trip=0.f, dc=0.f, nv=0.f, ce=0.f;
    if (ok){
      float dpos = sqrtf(dp2), dneg = sqrtf(dn2);
      trip = fmaxf(dpos - dneg + 0.5f, 0.f);
      float mn = sqrtf(mm), dnn = sqrtf(dd);
      bool valid = (mn > 1e-6f) && (dnn > 1e-6f);
      float cosv = md / ((mn + 1e-8f)*(dnn + 1e-8f));
      if (valid){ dc = 1.f - cosv; nv = 1.f; }
      ce = lse2[n] - (fmaf(dt, S20F, -c2s[tg]));
    }
    for (int off=1; off<64; off<<=1){
      trip += __shfl_xor(trip,off);
      dc   += __shfl_xor(dc,off);
      nv   += __shfl_xor(nv,off);
      dp2  += __shfl_xor(dp2,off);
      ce   += __shfl_xor(ce,off);
    }
    if (tt == 0){
      atomicAdd(&accs[0], trip); atomicAdd(&accs[1], dc);
      atomicAdd(&accs[2], nv);   atomicAdd(&accs[3], dp2);
      atomicAdd(&accs[4], ce);
    }
  }
}

__global__ void k_total(const float* __restrict__ accs, float* __restrict__ out){
  float feat = accs[3] / 6144000.f;         // 8*512*1500
  float trip = accs[0] / (float)NN;
  float ce   = (accs[4] / (float)NN) * LN2F;
  float nv   = accs[2] < 1.f ? 1.f : accs[2];
  float dc   = accs[1] / nv;
  out[0] = 2.f*feat + trip + ce + dc;
}

extern "C" void kernel_launch(void* const* d_in, const int* in_sizes, int n_in,
                              void* d_out, int out_size, void* d_ws, size_t ws_size,
                              hipStream_t stream){
  const float* student = (const float*)d_in[0];
  const float* teacher = (const float*)d_in[1];
  const float* cb      = (const float*)d_in[2];
  const int*   codes   = (const int*)d_in[3];
  const float* orig    = (const float*)d_in[4];

  char* ws = (char*)d_ws;
  ushort* zbf    = (ushort*)(ws);                  // 12032*512*2 = 12,320,768
  ushort* cbsw   = (ushort*)(ws + 12320768);       // 4,194,304
  float*  c2s    = (float*)(ws + 16515072);        // 16,384
  float4* pstate = (float4*)(ws + 16531456);       // 8*12032*16 = 1,540,096
  float*  lse2   = (float*)(ws + 18071552);        // 48,128
  int*    hard   = (int*)(ws + 18119680);          // 48,128
  float*  accs   = (float*)(ws + 18167808);        // 8 floats
  hipMemsetAsync(ws + 18167808, 0, 64, stream);
  k_prep_cb<<<1024, 256, 0, stream>>>(cb, cbsw);
  k_c2<<<1024, 256, 0, stream>>>(cb, c2s);
  k_prep_z<<<dim3(24, 8, 8), 256, 0, stream>>>(student, zbf);
  k_dist<<<dim3(8, 94), 512, 0, stream>>>(zbf, cbsw, c2s, codes, pstate);
  k_merge<<<47, 256, 0, stream>>>(pstate, lse2, hard);
  k_final<<<188, 256, 0, stream>>>(student, teacher, orig, cb, hard, codes, lse2, c2s, accs);
  k_total<<<1, 1, 0, stream>>>(accs, (float*)d_out);
}